// Round 4
// baseline (536.523 us; speedup 1.0000x reference)
//
#include <hip/hip_runtime.h>

#define N_NODES   150000
#define N_PAD     150016   // 4688 * 32
#define B_EDGES   16384
#define H         128
#define KP        192      // padded K: 2 cont + 48 cat + 128 h + 14 zero
#define N_NCAT    3
#define NCAT_CARD 64
#define NCAT_DIM  16
#define N_ETYPES  1000
#define ETYPE_DIM 32
#define N_ECAT    2
#define ECAT_CARD 32
#define ECAT_DIM  16
#define T_DIM     16
#define P_IN      336
#define P_HID     64

typedef __bf16 bf16x8 __attribute__((ext_vector_type(8)));
typedef float  f32x4  __attribute__((ext_vector_type(4)));
typedef unsigned int u32x4 __attribute__((ext_vector_type(4)));

__device__ __forceinline__ float rcp_(float x)      { return __builtin_amdgcn_rcpf(x); }
__device__ __forceinline__ float sigmoidf_(float x) { return rcp_(1.0f + __expf(-x)); }
__device__ __forceinline__ float tanhf_(float x)    { return 1.0f - 2.0f * rcp_(__expf(2.0f * x) + 1.0f); }
__device__ __forceinline__ unsigned short f2bf(float f) {
    unsigned u = __float_as_uint(f);
    u += 0x7fffu + ((u >> 16) & 1u);   // RNE
    return (unsigned short)(u >> 16);
}

// ---------------------------------------------------------------------------
// Prepass: Wt_bf16[512][192] with GATE-IN-LANE channel ordering.
// c bits: [8]=cb, [7:6]=wv, [5:4]=gate, [3:0]=m16; h = cb*64 + wv*16 + m16.
// Fused kernel wave wv (of 4) at block cb covers c in [cb*256+wv*64, +64):
// gate = ni, h = cb*64 + wv*16 + m16 -> all 4 gates of one h in one lane.
// ---------------------------------------------------------------------------
__global__ __launch_bounds__(192) void build_w_kernel(
    const float* __restrict__ Wx, const float* __restrict__ Wh,
    unsigned short* __restrict__ Wt)
{
    const int c = blockIdx.x, k = threadIdx.x;
    const int m16 = c & 15;
    const int g   = (c >> 4) & 3;
    const int w   = (c >> 6) & 3;
    const int cbh = c >> 8;
    const int h   = cbh * 64 + w * 16 + m16;
    float v = 0.0f;
    if (k < 50)       v = Wx[(g * 50 + k) * H + h];
    else if (k < 178) v = Wh[(g * H + (k - 50)) * H + h];
    Wt[c * KP + k] = f2bf(v);
}

// ---------------------------------------------------------------------------
// Fused: A-tile gather/convert -> LDS (XOR atom swizzle) -> MFMA GEMM ->
// in-register peephole-LSTM epilogue.
// Block = 32 nodes x 256 cpos (4 waves, 256 thr); grid (2, 4688), x fastest
// so the paired block re-gathering the same node rows runs back-to-back
// (second fetch L3-hit).  acc[2][4] = 32 AGPRs/wave -> ~5 waves/SIMD
// resident (vs 4 at round-3's 64-reg clamp) + finer block granularity.
// c_prev prefetched BEFORE the MFMA loop (round-3 regression: cold post-MFMA
// stall when it moved to the epilogue).
// ---------------------------------------------------------------------------
__global__ __launch_bounds__(256) void lstm_mfma_fused(
    const float* __restrict__ node_cont,
    const int*   __restrict__ node_cat_codes,
    const float* __restrict__ node_cat_emb,
    const float* __restrict__ h_prev,
    const unsigned short* __restrict__ Wt,   // [512][192], gate-in-lane order
    const float* __restrict__ c_prev,
    const float* __restrict__ b_gate,        // (4,128)
    const float* __restrict__ w_c,           // (3,128)
    float* __restrict__ h_out,
    float* __restrict__ c_out)
{
    // [6 kc][32 rows][32 shorts]; atom (16B) index XOR-swizzled by (row>>1)&3.
    __shared__ __align__(16) unsigned short Asub[6 * 32 * 32];   // 12 KB

    const int t     = threadIdx.x;
    const int cb    = blockIdx.x;            // channel half
    const int nbase = blockIdx.y * 32;       // node tile (32 nodes)

    // ---- build phase: gather + bf16-convert the 32x192 A-tile into LDS ----
    {
        const int brow  = t >> 3;            // 0..31
        const int bsub  = t & 7;
        const int bnode = nbase + brow;
        const bool valid = bnode < N_NODES;
        #pragma unroll
        for (int s = 0; s < 3; ++s) {
            const int at = bsub + s * 8;     // global atom 0..23 (8 cols each)
            const int j0 = at * 8;
            float v[8];
            #pragma unroll
            for (int e = 0; e < 8; ++e) {
                const int j = j0 + e;
                float x = 0.0f;
                if (valid) {
                    if (j < 2) {
                        x = node_cont[bnode * 2 + j];
                    } else if (j < 50) {
                        int c = (j - 2) >> 4, d = (j - 2) & 15;
                        int code = node_cat_codes[c * N_NODES + bnode];
                        x = node_cat_emb[(c * NCAT_CARD + code) * NCAT_DIM + d];
                    } else if (j < 178) {
                        x = h_prev[(size_t)bnode * H + (j - 50)];
                    }
                }
                v[e] = x;
            }
            unsigned u[4];
            #pragma unroll
            for (int p = 0; p < 4; ++p)
                u[p] = (unsigned)f2bf(v[2 * p]) | ((unsigned)f2bf(v[2 * p + 1]) << 16);
            const int kc = at >> 2, a = at & 3;
            const int as = a ^ ((brow >> 1) & 3);
            *(u32x4*)&Asub[(kc * 32 + brow) * 32 + as * 8] = *(const u32x4*)u;
        }
    }

    // ---- wave coordinates (computed before barrier; c_prev issued early) ----
    const int wv   = t >> 6, ln = t & 63;
    const int quad = ln >> 4, m16 = ln & 15;
    const int h    = cb * 64 + wv * 16 + m16;    // this lane's h (fixed)

    // Early c_prev prefetch: 8 independent loads, latency hides under barrier
    // wait + MFMA loop.
    float cpv[2][4];
    #pragma unroll
    for (int mi = 0; mi < 2; ++mi)
        #pragma unroll
        for (int r = 0; r < 4; ++r) {
            const int node = nbase + mi * 16 + quad * 4 + r;
            cpv[mi][r] = (node < N_NODES) ? c_prev[(size_t)node * H + h] : 0.0f;
        }

    const unsigned short* wptr[4];
    #pragma unroll
    for (int ni = 0; ni < 4; ++ni)
        wptr[ni] = Wt + (size_t)(cb * 256 + wv * 64 + ni * 16 + m16) * KP + quad * 8;

    __syncthreads();

    // ---- MFMA phase: wave owns 32 nodes x 64 cpos; 48 MFMAs, no barriers ----
    f32x4 acc[2][4];
    #pragma unroll
    for (int i = 0; i < 2; ++i)
        #pragma unroll
        for (int j = 0; j < 4; ++j) acc[i][j] = (f32x4){0.f, 0.f, 0.f, 0.f};

    #pragma unroll
    for (int kc = 0; kc < 6; ++kc) {
        bf16x8 af[2], bf[4];
        #pragma unroll
        for (int mi = 0; mi < 2; ++mi) {
            const int row = mi * 16 + m16;
            const int as  = quad ^ ((row >> 1) & 3);
            af[mi] = *(const bf16x8*)&Asub[(kc * 32 + row) * 32 + as * 8];
        }
        #pragma unroll
        for (int ni = 0; ni < 4; ++ni)
            bf[ni] = *(const bf16x8*)(wptr[ni] + kc * 32);
        #pragma unroll
        for (int mi = 0; mi < 2; ++mi)
            #pragma unroll
            for (int ni = 0; ni < 4; ++ni)
                acc[mi][ni] = __builtin_amdgcn_mfma_f32_16x16x32_bf16(
                    af[mi], bf[ni], acc[mi][ni], 0, 0, 0);
    }

    // ---- epilogue: all 4 gates of this lane's h are in acc[mi][0..3][r] ----
    const float bg0 = b_gate[0 * H + h], bg1 = b_gate[1 * H + h];
    const float bg2 = b_gate[2 * H + h], bg3 = b_gate[3 * H + h];
    const float wc0 = w_c[0 * H + h], wc1 = w_c[1 * H + h], wc2 = w_c[2 * H + h];

    #pragma unroll
    for (int mi = 0; mi < 2; ++mi)
        #pragma unroll
        for (int r = 0; r < 4; ++r) {
            const int node = nbase + mi * 16 + quad * 4 + r;
            if (node < N_NODES) {
                const size_t off = (size_t)node * H + h;
                const float cp = cpv[mi][r];
                float ig = sigmoidf_(acc[mi][0][r] + bg0 + wc0 * cp);
                float fg = sigmoidf_(acc[mi][1][r] + bg1 + wc1 * cp);
                float tg = tanhf_(acc[mi][2][r] + bg2);
                float cn = fg * cp + ig * tg;
                float og = sigmoidf_(acc[mi][3][r] + bg3 + wc2 * cn);
                h_out[off] = og * tanhf_(cn);
                c_out[off] = cn;
            }
        }
}

// ---------------------------------------------------------------------------
// Edge MLP: one wave per edge, 4 edges/block; 4-way ILP + float4 LDS reads.
// (unchanged — known-good)
// ---------------------------------------------------------------------------
__global__ __launch_bounds__(256) void edge_kernel(
    const int*   __restrict__ src,
    const int*   __restrict__ dst,
    const int*   __restrict__ et,
    const float* __restrict__ t_rel,
    const int*   __restrict__ edge_cat_codes,
    const float* __restrict__ edge_id_emb,
    const float* __restrict__ edge_cat_emb,
    const float* __restrict__ time_W,
    const float* __restrict__ time_b,
    const float* __restrict__ W1,
    const float* __restrict__ b1,
    const float* __restrict__ W2,
    const float* __restrict__ b2,
    const float* __restrict__ h_new,
    float* __restrict__ prob)
{
    __shared__ __align__(16) float comb[4][P_IN];
    const int t = threadIdx.x;
    const int el = t >> 6;
    const int j  = t & 63;
    const int e  = blockIdx.x * 4 + el;

    if (e < B_EDGES) {
        const int s = src[e], d = dst[e], ety = et[e];
        comb[el][j]       = h_new[(size_t)s * H + j];
        comb[el][64 + j]  = h_new[(size_t)s * H + 64 + j];
        comb[el][128 + j] = h_new[(size_t)d * H + j];
        comb[el][192 + j] = h_new[(size_t)d * H + 64 + j];
        if (j < 32) {
            comb[el][256 + j] = edge_id_emb[ety * ETYPE_DIM + j];
            int c = j >> 4, dd = j & 15;
            int code = edge_cat_codes[c * N_ETYPES + ety];
            comb[el][288 + j] = edge_cat_emb[(c * ECAT_CARD + code) * ECAT_DIM + dd];
        }
        if (j < T_DIM) comb[el][320 + j] = t_rel[e] * time_W[j] + time_b[j];
    }
    __syncthreads();
    if (e >= B_EDGES) return;

    float h0 = b1[j], h1 = 0.f, h2 = 0.f, h3 = 0.f;
    #pragma unroll 4
    for (int k = 0; k < P_IN; k += 4) {
        float4 cv = *(const float4*)&comb[el][k];
        h0 = fmaf(cv.x, W1[(k + 0) * P_HID + j], h0);
        h1 = fmaf(cv.y, W1[(k + 1) * P_HID + j], h1);
        h2 = fmaf(cv.z, W1[(k + 2) * P_HID + j], h2);
        h3 = fmaf(cv.w, W1[(k + 3) * P_HID + j], h3);
    }
    float hid = fmaxf((h0 + h1) + (h2 + h3), 0.0f);

    float v = hid * W2[j];
    #pragma unroll
    for (int off = 32; off > 0; off >>= 1) v += __shfl_down(v, off);
    if (j == 0) prob[e] = sigmoidf_(v + b2[0]);
}

extern "C" void kernel_launch(void* const* d_in, const int* in_sizes, int n_in,
                              void* d_out, int out_size, void* d_ws, size_t ws_size,
                              hipStream_t stream) {
    const int*   src            = (const int*)  d_in[0];
    const int*   dst            = (const int*)  d_in[1];
    const int*   et             = (const int*)  d_in[2];
    const float* t_rel          = (const float*)d_in[3];
    const float* node_cont      = (const float*)d_in[4];
    const int*   node_cat_codes = (const int*)  d_in[5];
    const int*   edge_cat_codes = (const int*)  d_in[6];
    const float* h_prev         = (const float*)d_in[8];
    const float* c_prev         = (const float*)d_in[9];
    const float* node_cat_emb   = (const float*)d_in[10];
    const float* edge_id_emb    = (const float*)d_in[11];
    const float* edge_cat_emb   = (const float*)d_in[12];
    const float* time_W         = (const float*)d_in[13];
    const float* time_b         = (const float*)d_in[14];
    const float* Wx             = (const float*)d_in[15];
    const float* Wh             = (const float*)d_in[16];
    const float* b_gate         = (const float*)d_in[17];
    const float* w_c            = (const float*)d_in[18];
    const float* W1             = (const float*)d_in[19];
    const float* b1             = (const float*)d_in[20];
    const float* W2             = (const float*)d_in[21];
    const float* b2             = (const float*)d_in[22];

    float* out   = (float*)d_out;
    float* prob  = out;
    float* h_out = out + B_EDGES;
    float* c_out = out + B_EDGES + (size_t)N_NODES * H;

    unsigned short* Wt = (unsigned short*)d_ws;   // 196 KB only

    build_w_kernel<<<512, 192, 0, stream>>>(Wx, Wh, Wt);

    dim3 grid(2, N_PAD / 32);   // (2, 4688), x (channel half) fastest
    lstm_mfma_fused<<<grid, 256, 0, stream>>>(
        node_cont, node_cat_codes, node_cat_emb, h_prev, Wt, c_prev,
        b_gate, w_c, h_out, c_out);

    edge_kernel<<<B_EDGES / 4, 256, 0, stream>>>(src, dst, et, t_rel,
                                                 edge_cat_codes, edge_id_emb, edge_cat_emb,
                                                 time_W, time_b, W1, b1, W2, b2,
                                                 h_out, prob);
}

// Round 5
// 440.122 us; speedup vs baseline: 1.2190x; 1.2190x over previous
//
#include <hip/hip_runtime.h>

#define N_NODES   150000
#define N_PAD     150016   // 2344 * 64
#define B_EDGES   16384
#define H         128
#define KP        192      // padded K: 128 h | 2 cont | 48 cat | 14 zero
#define N_NCAT    3
#define NCAT_CARD 64
#define NCAT_DIM  16
#define N_ETYPES  1000
#define ETYPE_DIM 32
#define N_ECAT    2
#define ECAT_CARD 32
#define ECAT_DIM  16
#define T_DIM     16
#define P_IN      336
#define P_HID     64

typedef __bf16 bf16x8 __attribute__((ext_vector_type(8)));
typedef float  f32x4  __attribute__((ext_vector_type(4)));
typedef unsigned int u32x4 __attribute__((ext_vector_type(4)));
typedef unsigned int u32x2 __attribute__((ext_vector_type(2)));

__device__ __forceinline__ float rcp_(float x)      { return __builtin_amdgcn_rcpf(x); }
__device__ __forceinline__ float sigmoidf_(float x) { return rcp_(1.0f + __expf(-x)); }
__device__ __forceinline__ float tanhf_(float x)    { return 1.0f - 2.0f * rcp_(__expf(2.0f * x) + 1.0f); }
__device__ __forceinline__ unsigned short f2bf(float f) {
    unsigned u = __float_as_uint(f);
    u += 0x7fffu + ((u >> 16) & 1u);   // RNE
    return (unsigned short)(u >> 16);
}
__device__ __forceinline__ float bf2f(unsigned short b) {
    return __uint_as_float((unsigned)b << 16);
}

// ---------------------------------------------------------------------------
// Prepass: Wt_bf16[512][192], k-order [h(128)|cont(2)|cat(48)|pad(14)],
// GATE-IN-LANE channel ordering: c bits [8]=cb,[7:6]=wv,[5:4]=gate,[3:0]=m16,
// h = cb*64 + wv*16 + m16 -> all 4 gates of one h land in one lane's acc.
// ---------------------------------------------------------------------------
__global__ __launch_bounds__(192) void build_w_kernel(
    const float* __restrict__ Wx, const float* __restrict__ Wh,
    unsigned short* __restrict__ Wt)
{
    const int c = blockIdx.x, k = threadIdx.x;
    const int m16 = c & 15;
    const int g   = (c >> 4) & 3;
    const int w   = (c >> 6) & 3;
    const int cbh = c >> 8;
    const int h   = cbh * 64 + w * 16 + m16;
    float v = 0.0f;
    if (k < 128)      v = Wh[(g * H + k) * H + h];          // h_prev part first
    else if (k < 178) v = Wx[(g * 50 + (k - 128)) * H + h]; // cont(2)+cat(48)
    Wt[c * KP + k] = f2bf(v);
}

// ---------------------------------------------------------------------------
// Fused: A-tile gather/convert -> LDS (XOR atom swizzle) -> MFMA GEMM ->
// in-register peephole-LSTM epilogue.  Round-3 geometry: block = 64 nodes x
// 512 cpos, 8 waves; grid 2344.  Changes vs round 3:
//  - k-layout puts h_prev first: gather atoms 0..15 are two aligned float4
//    loads each (h-region load instrs /4, coalesced 8-lane row spans)
//  - c_prev prefetched BEFORE the barrier (round-3 cold post-MFMA stall)
//  - launch_bounds (512,3): arch VGPR budget ~106 so the prefetch fits
// ---------------------------------------------------------------------------
__global__ __launch_bounds__(512, 3) void lstm_mfma_fused(
    const float* __restrict__ node_cont,
    const int*   __restrict__ node_cat_codes,
    const float* __restrict__ node_cat_emb,
    const float* __restrict__ h_prev,
    const unsigned short* __restrict__ Wt,   // [512][192]
    const float* __restrict__ c_prev,
    const float* __restrict__ b_gate,        // (4,128)
    const float* __restrict__ w_c,           // (3,128)
    float* __restrict__ h_out,
    float* __restrict__ c_out)
{
    // [6 kc][64 rows][32 shorts]; atom (16B) index XOR-swizzled by (row>>1)&3.
    __shared__ __align__(16) unsigned short Asub[6 * 64 * 32];   // 24 KB

    const int t     = threadIdx.x;
    const int nbase = blockIdx.x * 64;

    // ---- build phase: gather + bf16-convert the 64x192 A-tile into LDS ----
    {
        const int brow  = t >> 3;            // 0..63
        const int bsub  = t & 7;
        const int bnode = nbase + brow;
        const bool valid = bnode < N_NODES;
        const int swz = (brow >> 1) & 3;

        // atoms 0..15: pure h_prev, two aligned float4 loads per atom
        #pragma unroll
        for (int s = 0; s < 2; ++s) {
            const int at = bsub + s * 8;     // 0..15
            float4 v0 = {0.f,0.f,0.f,0.f}, v1 = {0.f,0.f,0.f,0.f};
            if (valid) {
                const float* hp = h_prev + (size_t)bnode * H + at * 8;
                v0 = *(const float4*)hp;
                v1 = *(const float4*)(hp + 4);
            }
            unsigned u[4];
            u[0] = (unsigned)f2bf(v0.x) | ((unsigned)f2bf(v0.y) << 16);
            u[1] = (unsigned)f2bf(v0.z) | ((unsigned)f2bf(v0.w) << 16);
            u[2] = (unsigned)f2bf(v1.x) | ((unsigned)f2bf(v1.y) << 16);
            u[3] = (unsigned)f2bf(v1.z) | ((unsigned)f2bf(v1.w) << 16);
            const int kc = at >> 2, a = at & 3, as = a ^ swz;
            *(u32x4*)&Asub[(kc * 64 + brow) * 32 + as * 8] = *(const u32x4*)u;
        }

        // atoms 16..23: cont(2) + cat(48) + pad; d_in idx = bsub*8 + e
        {
            const int at = 16 + bsub;
            float v[8];
            #pragma unroll
            for (int e = 0; e < 8; ++e) {
                const int idx = bsub * 8 + e;    // 0..63
                float x = 0.0f;
                if (valid) {
                    if (idx < 2) {
                        x = node_cont[bnode * 2 + idx];
                    } else if (idx < 50) {
                        int c = (idx - 2) >> 4, d = (idx - 2) & 15;
                        int code = node_cat_codes[c * N_NODES + bnode];
                        x = node_cat_emb[(c * NCAT_CARD + code) * NCAT_DIM + d];
                    }
                }
                v[e] = x;
            }
            unsigned u[4];
            #pragma unroll
            for (int p = 0; p < 4; ++p)
                u[p] = (unsigned)f2bf(v[2 * p]) | ((unsigned)f2bf(v[2 * p + 1]) << 16);
            const int kc = at >> 2, a = at & 3, as = a ^ swz;
            *(u32x4*)&Asub[(kc * 64 + brow) * 32 + as * 8] = *(const u32x4*)u;
        }
    }

    // ---- wave coords + early c_prev prefetch (hides under barrier+MFMA) ----
    const int wv   = t >> 6, ln = t & 63;
    const int quad = ln >> 4, m16 = ln & 15;
    const int h    = (wv >> 2) * 64 + (wv & 3) * 16 + m16;   // lane's h (fixed)

    float cpv[4][4];
    #pragma unroll
    for (int mi = 0; mi < 4; ++mi)
        #pragma unroll
        for (int r = 0; r < 4; ++r) {
            const int node = nbase + mi * 16 + quad * 4 + r;
            cpv[mi][r] = (node < N_NODES) ? c_prev[(size_t)node * H + h] : 0.0f;
        }

    const unsigned short* wptr[4];
    #pragma unroll
    for (int ni = 0; ni < 4; ++ni)
        wptr[ni] = Wt + (size_t)(wv * 64 + ni * 16 + m16) * KP + quad * 8;

    __syncthreads();

    // ---- MFMA phase: wave owns 64 nodes x 64 cpos; 96 MFMAs, no barriers ----
    f32x4 acc[4][4];
    #pragma unroll
    for (int i = 0; i < 4; ++i)
        #pragma unroll
        for (int j = 0; j < 4; ++j) acc[i][j] = (f32x4){0.f, 0.f, 0.f, 0.f};

    #pragma unroll
    for (int kc = 0; kc < 6; ++kc) {
        bf16x8 af[4], bf[4];
        #pragma unroll
        for (int mi = 0; mi < 4; ++mi) {
            const int row = mi * 16 + m16;
            const int as  = quad ^ ((row >> 1) & 3);
            af[mi] = *(const bf16x8*)&Asub[(kc * 64 + row) * 32 + as * 8];
        }
        #pragma unroll
        for (int ni = 0; ni < 4; ++ni)
            bf[ni] = *(const bf16x8*)(wptr[ni] + kc * 32);
        #pragma unroll
        for (int mi = 0; mi < 4; ++mi)
            #pragma unroll
            for (int ni = 0; ni < 4; ++ni)
                acc[mi][ni] = __builtin_amdgcn_mfma_f32_16x16x32_bf16(
                    af[mi], bf[ni], acc[mi][ni], 0, 0, 0);
    }

    // ---- epilogue: all 4 gates of this lane's h are in acc[mi][0..3][r] ----
    const float bg0 = b_gate[0 * H + h], bg1 = b_gate[1 * H + h];
    const float bg2 = b_gate[2 * H + h], bg3 = b_gate[3 * H + h];
    const float wc0 = w_c[0 * H + h], wc1 = w_c[1 * H + h], wc2 = w_c[2 * H + h];

    #pragma unroll
    for (int mi = 0; mi < 4; ++mi)
        #pragma unroll
        for (int r = 0; r < 4; ++r) {
            const int node = nbase + mi * 16 + quad * 4 + r;
            if (node < N_NODES) {
                const size_t off = (size_t)node * H + h;
                const float cp = cpv[mi][r];
                float ig = sigmoidf_(acc[mi][0][r] + bg0 + wc0 * cp);
                float fg = sigmoidf_(acc[mi][1][r] + bg1 + wc1 * cp);
                float tg = tanhf_(acc[mi][2][r] + bg2);
                float cn = fg * cp + ig * tg;
                float og = sigmoidf_(acc[mi][3][r] + bg3 + wc2 * cn);
                h_out[off] = og * tanhf_(cn);
                c_out[off] = cn;
            }
        }
}

// ---------------------------------------------------------------------------
// Edge MLP v2: 16 edges/block (1024 blocks).  W1 staged ONCE per block into
// LDS as bf16 (43 KB) -> W1 L2 traffic 1.4 GB -> 88 MB.  comb f32 in LDS
// (16 x 340 incl. pad for float4 alignment).  Compute: 4 edges/wave, lane =
// hid channel; comb read via b128 broadcast, W1 via conflict-free u16.
// ---------------------------------------------------------------------------
#define CPAD 340
__global__ __launch_bounds__(256) void edge_kernel(
    const int*   __restrict__ src,
    const int*   __restrict__ dst,
    const int*   __restrict__ et,
    const float* __restrict__ t_rel,
    const int*   __restrict__ edge_cat_codes,
    const float* __restrict__ edge_id_emb,
    const float* __restrict__ edge_cat_emb,
    const float* __restrict__ time_W,
    const float* __restrict__ time_b,
    const float* __restrict__ W1,
    const float* __restrict__ b1,
    const float* __restrict__ W2,
    const float* __restrict__ b2,
    const float* __restrict__ h_new,
    float* __restrict__ prob)
{
    __shared__ __align__(16) unsigned short W1s[P_IN * P_HID];  // 43008 B
    __shared__ __align__(16) float comb[16][CPAD];              // 21760 B

    const int t = threadIdx.x;

    // ---- stage W1 -> bf16 LDS (21504 f32; 21 x float4 per thread) ----
    #pragma unroll
    for (int i = 0; i < 21; ++i) {
        const int idx = (i * 256 + t) * 4;       // 0..21500, exact cover
        float4 w = *(const float4*)&W1[idx];
        unsigned u[2];
        u[0] = (unsigned)f2bf(w.x) | ((unsigned)f2bf(w.y) << 16);
        u[1] = (unsigned)f2bf(w.z) | ((unsigned)f2bf(w.w) << 16);
        *(u32x2*)&W1s[idx] = *(const u32x2*)u;
    }

    // ---- gather comb: 16 threads per edge ----
    const int el = t >> 4, p = t & 15;
    const int e  = blockIdx.x * 16 + el;
    if (e < B_EDGES) {
        const int s = src[e], d = dst[e], ety = et[e];
        const float tr = t_rel[e];
        // h parts: p<8 -> src h[p*16..], p>=8 -> dst h[(p-8)*16..]; dest = p*16
        const float* hp = (p < 8) ? (h_new + (size_t)s * H + p * 16)
                                  : (h_new + (size_t)d * H + (p - 8) * 16);
        #pragma unroll
        for (int q = 0; q < 4; ++q)
            *(float4*)&comb[el][p * 16 + q * 4] = *(const float4*)(hp + q * 4);
        // edge feats: elems 256..335, f = p + q*16
        #pragma unroll
        for (int q = 0; q < 5; ++q) {
            const int f = p + q * 16;            // 0..79
            float x;
            if (f < 32) {
                x = edge_id_emb[ety * ETYPE_DIM + f];
            } else if (f < 64) {
                int c = (f - 32) >> 4, dd = (f - 32) & 15;
                int code = edge_cat_codes[c * N_ETYPES + ety];
                x = edge_cat_emb[(c * ECAT_CARD + code) * ECAT_DIM + dd];
            } else {
                x = tr * time_W[f - 64] + time_b[f - 64];
            }
            comb[el][256 + f] = x;
        }
    }
    __syncthreads();

    // ---- compute: wave wv -> edges wv*4..+3; lane j = hid channel ----
    const int wv = t >> 6, j = t & 63;
    const int ebase = blockIdx.x * 16 + wv * 4;
    float a0 = b1[j], a1 = b1[j], a2 = b1[j], a3 = b1[j];
    const float* c0 = comb[wv * 4 + 0];
    const float* c1 = comb[wv * 4 + 1];
    const float* c2 = comb[wv * 4 + 2];
    const float* c3 = comb[wv * 4 + 3];
    #pragma unroll 4
    for (int k4 = 0; k4 < P_IN; k4 += 4) {
        float4 v0 = *(const float4*)&c0[k4];
        float4 v1 = *(const float4*)&c1[k4];
        float4 v2 = *(const float4*)&c2[k4];
        float4 v3 = *(const float4*)&c3[k4];
        #pragma unroll
        for (int kk = 0; kk < 4; ++kk) {
            const float w = bf2f(W1s[(k4 + kk) * P_HID + j]);
            const float* pv0 = (const float*)&v0;
            const float* pv1 = (const float*)&v1;
            const float* pv2 = (const float*)&v2;
            const float* pv3 = (const float*)&v3;
            a0 = fmaf(pv0[kk], w, a0);
            a1 = fmaf(pv1[kk], w, a1);
            a2 = fmaf(pv2[kk], w, a2);
            a3 = fmaf(pv3[kk], w, a3);
        }
    }
    const float w2 = W2[j];
    float v;
    #define REDUCE_WRITE(ACC, EOFF)                                   \
        v = fmaxf(ACC, 0.0f) * w2;                                    \
        _Pragma("unroll")                                             \
        for (int off = 32; off > 0; off >>= 1) v += __shfl_down(v, off); \
        if (j == 0 && (ebase + EOFF) < B_EDGES)                       \
            prob[ebase + EOFF] = sigmoidf_(v + b2[0]);
    REDUCE_WRITE(a0, 0)
    REDUCE_WRITE(a1, 1)
    REDUCE_WRITE(a2, 2)
    REDUCE_WRITE(a3, 3)
    #undef REDUCE_WRITE
}

extern "C" void kernel_launch(void* const* d_in, const int* in_sizes, int n_in,
                              void* d_out, int out_size, void* d_ws, size_t ws_size,
                              hipStream_t stream) {
    const int*   src            = (const int*)  d_in[0];
    const int*   dst            = (const int*)  d_in[1];
    const int*   et             = (const int*)  d_in[2];
    const float* t_rel          = (const float*)d_in[3];
    const float* node_cont      = (const float*)d_in[4];
    const int*   node_cat_codes = (const int*)  d_in[5];
    const int*   edge_cat_codes = (const int*)  d_in[6];
    const float* h_prev         = (const float*)d_in[8];
    const float* c_prev         = (const float*)d_in[9];
    const float* node_cat_emb   = (const float*)d_in[10];
    const float* edge_id_emb    = (const float*)d_in[11];
    const float* edge_cat_emb   = (const float*)d_in[12];
    const float* time_W         = (const float*)d_in[13];
    const float* time_b         = (const float*)d_in[14];
    const float* Wx             = (const float*)d_in[15];
    const float* Wh             = (const float*)d_in[16];
    const float* b_gate         = (const float*)d_in[17];
    const float* w_c            = (const float*)d_in[18];
    const float* W1             = (const float*)d_in[19];
    const float* b1             = (const float*)d_in[20];
    const float* W2             = (const float*)d_in[21];
    const float* b2             = (const float*)d_in[22];

    float* out   = (float*)d_out;
    float* prob  = out;
    float* h_out = out + B_EDGES;
    float* c_out = out + B_EDGES + (size_t)N_NODES * H;

    unsigned short* Wt = (unsigned short*)d_ws;   // 196 KB only

    build_w_kernel<<<512, 192, 0, stream>>>(Wx, Wh, Wt);

    lstm_mfma_fused<<<N_PAD / 64, 512, 0, stream>>>(
        node_cont, node_cat_codes, node_cat_emb, h_prev, Wt, c_prev,
        b_gate, w_c, h_out, c_out);

    edge_kernel<<<B_EDGES / 16, 256, 0, stream>>>(src, dst, et, t_rel,
                                                  edge_cat_codes, edge_id_emb, edge_cat_emb,
                                                  time_W, time_b, W1, b1, W2, b2,
                                                  h_out, prob);
}